// Round 7
// baseline (7257.928 us; speedup 1.0000x reference)
//
#include <hip/hip_runtime.h>

// Farthest Point Sampling: points (B, N, 3) fp32 -> indices (B, M) int32.
// B=16, N=65536, M=2048.  Reference semantics (locked in R2, absmax=0):
// float64 pipeline: dx=(double)x-(double)cx; d=((dx*dx+dy*dy)+dz*dz) with
// separate rounding (no FMA); min via fmin; argmax first-index tie-break.
//
// Round 7: XCD co-location. R6's per-iter 2.85 us was ~2.2 us fabric latency:
// dim3(16,16) spread each batch's 16 blocks across all 8 XCDs, so every
// publish/poll crossed the coherence point (FETCH 277 MB = poll misses).
// Now: flat grid 256, batch = id & 15, rank = id >> 4. Batch b's blocks all
// have id == b (mod 8) -> round-robin dispatch puts them on ONE XCD (b%8,
// 32 blocks = 32 CUs/XCD, two batches per XCD). A batch's ws slot lines are
// then touched only from that XCD -> resident in its local L2: publish ~100
// cyc, poll ~200 cyc, no cross-XCD traffic. Heuristic only - correctness
// does not depend on placement (agent-scope atomics).
//
// Barrier protocol (unchanged from R6): 4 self-tagged 8-B relaxed atomic
// words per 128-B slot, per (parity, batch, rank):
//   A = value_lo32<<32 | m<<16 | idx        (idx<65536, m<2048: 16b each)
//   B = value_hi32<<32 | m<<16 | idx
//   C = x_bits<<32     | m<<16 | y_hi16
//   D = y_lo16<<48     | z_bits<<16 | m
// Aligned 8-B stores are single-copy atomic; every word carries m, so epoch
// mixes are detected and re-polled. No release, no acquire, no fences ->
// caches stay warm. Reuse safety: slot rewritten at m+2 only after its
// writer saw all tags m+1, which post only after every block read m.
// 0xAA poison tag = 0xAAAA != any m in [1,2048) => no init kernel.

#define N_PTS   65536
#define M_SAMP  2048
#define NT      512
#define BPB     16                  // blocks per batch
#define PTS_BLK (N_PTS / BPB)       // 4096
#define PPT     (PTS_BLK / NT)      // 8 points per thread
#define NWAVES  (NT / 64)           // 8
#define NBATCH  16
#define SLOT_U64 16                 // 128 B per slot

typedef unsigned long long u64;

__device__ __forceinline__ u64 ld_agent(const u64* a) {
  return __hip_atomic_load(a, __ATOMIC_RELAXED, __HIP_MEMORY_SCOPE_AGENT);
}
__device__ __forceinline__ void st_agent(u64* a, u64 v) {
  __hip_atomic_store(a, v, __ATOMIC_RELAXED, __HIP_MEMORY_SCOPE_AGENT);
}

__global__ __launch_bounds__(NT, 2)
void fps_multi(const float* __restrict__ pts, int* __restrict__ out,
               u64* __restrict__ ws) {
  // XCD co-location swizzle: consecutive ids round-robin across XCDs, so
  // batch = id & 15 pins all 16 blocks of a batch to one XCD (id mod 8 const).
  const int b    = blockIdx.x & (NBATCH - 1);  // batch
  const int rank = blockIdx.x >> 4;            // 0..BPB-1 within batch
  const float* __restrict__ p = pts + (size_t)b * (size_t)(N_PTS * 3);
  int* __restrict__ o = out + (size_t)b * M_SAMP;
  const int t = threadIdx.x;
  const int base = rank * PTS_BLK;

  __shared__ float  s_pts[PTS_BLK * 3];        // 48 KB slice
  __shared__ double s_bv[NWAVES];
  __shared__ int    s_bi[NWAVES];
  __shared__ float  s_c[3];                    // broadcast centroid coords

  for (int i = t; i < PTS_BLK * 3; i += NT)
    s_pts[i] = p[base * 3 + i];
  if (rank == 0 && t == 0) o[0] = 0;
  if (t == 0) { s_c[0] = p[0]; s_c[1] = p[1]; s_c[2] = p[2]; }  // seed pt 0
  __syncthreads();

  // Own points pre-converted to f64 in registers; (double)x is exact.
  double pd[PPT][3];
  double md[PPT];
#pragma unroll
  for (int j = 0; j < PPT; ++j) {
    const int l = t + j * NT;
    pd[j][0] = (double)s_pts[3 * l + 0];
    pd[j][1] = (double)s_pts[3 * l + 1];
    pd[j][2] = (double)s_pts[3 * l + 2];
    md[j] = 1e10;
  }

  for (int m = 1; m < M_SAMP; ++m) {
    const double cx = (double)s_c[0];
    const double cy = (double)s_c[1];
    const double cz = (double)s_c[2];

    double bestv = -1.0;    // distances >= 0 always beat this
    int    besti = 0;

    // Indices base + t + j*NT ascend with j => strict '>' keeps the first
    // (lowest-index) maximum within a thread.
#pragma unroll
    for (int j = 0; j < PPT; ++j) {
      const double dx = __dsub_rn(pd[j][0], cx);
      const double dy = __dsub_rn(pd[j][1], cy);
      const double dz = __dsub_rn(pd[j][2], cz);
      const double d  = __dadd_rn(__dadd_rn(__dmul_rn(dx, dx),
                                            __dmul_rn(dy, dy)),
                                  __dmul_rn(dz, dz));
      const double nmd = fmin(md[j], d);
      md[j] = nmd;
      if (nmd > bestv) { bestv = nmd; besti = base + t + j * NT; }
    }

    // 64-lane butterfly argmax, min-index tie-break.
#pragma unroll
    for (int off = 32; off >= 1; off >>= 1) {
      const double ov = __shfl_xor(bestv, off, 64);
      const int    oi = __shfl_xor(besti, off, 64);
      if (ov > bestv || (ov == bestv && oi < besti)) { bestv = ov; besti = oi; }
    }
    if ((t & 63) == 0) { s_bv[t >> 6] = bestv; s_bi[t >> 6] = besti; }
    __syncthreads();

    // Wave 0: finish block reduction, publish, poll, cross-block reduce.
    if (t < 64) {
      if (t < NWAVES) {
        bestv = s_bv[t]; besti = s_bi[t];
#pragma unroll
        for (int off = NWAVES / 2; off >= 1; off >>= 1) {
          const double ov = __shfl_xor(bestv, off, 64);
          const int    oi = __shfl_xor(besti, off, 64);
          if (ov > bestv || (ov == bestv && oi < besti)) { bestv = ov; besti = oi; }
        }
      }
      const u64 mm  = (u64)(unsigned)m;
      const u64 grp = (u64)(((m & 1) * NBATCH + b) * BPB);
      if (t == 0) {
        u64* slot = ws + (grp + rank) * SLOT_U64;
        const int l = besti - base;           // block winner is in our slice
        const unsigned xb = __float_as_uint(s_pts[3 * l + 0]);
        const unsigned yb = __float_as_uint(s_pts[3 * l + 1]);
        const unsigned zb = __float_as_uint(s_pts[3 * l + 2]);
        const u64 vb = (u64)__double_as_longlong(bestv);
        const u64 ti = (mm << 16) | (u64)(unsigned)besti;
        st_agent(&slot[0], (vb << 32) | ti);                          // A
        st_agent(&slot[1], (vb & 0xFFFFFFFF00000000ull) | ti);        // B
        st_agent(&slot[2], ((u64)xb << 32) | (mm << 16) | (u64)(yb >> 16));          // C
        st_agent(&slot[3], ((u64)(yb & 0xFFFFu) << 48) | ((u64)zb << 16) | mm);      // D
      }
      if (t < BPB) {
        const u64* rs = ws + (grp + t) * SLOT_U64;
        u64 A, B, C, D;
        for (;;) {
          A = ld_agent(rs + 0);
          B = ld_agent(rs + 1);
          C = ld_agent(rs + 2);
          D = ld_agent(rs + 3);
          const bool ok = (((A >> 16) & 0xFFFFull) == mm) &
                          (((B >> 16) & 0xFFFFull) == mm) &
                          (((C >> 16) & 0xFFFFull) == mm) &
                          ((D & 0xFFFFull) == mm);
          if (ok) break;
        }
        double v = __longlong_as_double(
            (long long)((B & 0xFFFFFFFF00000000ull) | (A >> 32)));
        int   i = (int)(A & 0xFFFFull);
        float fx = __uint_as_float((unsigned)(C >> 32));
        float fy = __uint_as_float((unsigned)(((C & 0xFFFFull) << 16) | (D >> 48)));
        float fz = __uint_as_float((unsigned)((D >> 16) & 0xFFFFFFFFull));
        int r = t;                              // contributing rank
#pragma unroll
        for (int off = BPB / 2; off >= 1; off >>= 1) {
          const double ov = __shfl_xor(v, off, 64);
          const int    oi = __shfl_xor(i, off, 64);
          const int    orr = __shfl_xor(r, off, 64);
          if (ov > v || (ov == v && oi < i)) { v = ov; i = oi; r = orr; }
        }
        // Lanes 0..15 agree on winner rank r; pull its coords by shuffle.
        fx = __shfl(fx, r, 64);
        fy = __shfl(fy, r, 64);
        fz = __shfl(fz, r, 64);
        if (t == 0) {
          s_c[0] = fx; s_c[1] = fy; s_c[2] = fz;
          if (rank == 0) o[m] = i;
        }
      }
    }
    __syncthreads();
  }
}

extern "C" void kernel_launch(void* const* d_in, const int* in_sizes, int n_in,
                              void* d_out, int out_size, void* d_ws, size_t ws_size,
                              hipStream_t stream) {
  const float* pts = (const float*)d_in[0];
  int* out = (int*)d_out;
  const int B = in_sizes[0] / (N_PTS * 3);   // 16
  // ws usage: 2 * 16 * 16 slots * 128 B = 64 KB.
  hipLaunchKernelGGL(fps_multi, dim3(BPB * B), dim3(NT), 0, stream,
                     pts, out, (u64*)d_ws);
}

// Round 8
// 6138.486 us; speedup vs baseline: 1.1824x; 1.1824x over previous
//
#include <hip/hip_runtime.h>

// Farthest Point Sampling: points (B, N, 3) fp32 -> indices (B, M) int32.
// B=16, N=65536, M=2048.  Reference semantics (locked in R2, absmax=0):
// float64 pipeline: dx=(double)x-(double)cx; d=((dx*dx+dy*dy)+dz*dz) with
// separate rounding (no FMA); min via fmin; argmax first-index tie-break.
//
// Round 8: clock-boost experiment + u64-compare trims, on the proven R6
// structure (R7 showed the cross-XCD hop is NOT the critical path; R6 grid
// is robust to placement jitter, R7's co-location swizzle caused a 36.9 ms
// straggler outlier). Cycle model says the per-iter chain is ~3-3.9k cycles
// but measures 2.85 us => effective clock ~1.0-1.4 GHz: the latency-bound
// kernel (VALUBusy 19%) never trips DPM to boost SCLK.
//   - Blocks 0..255: workers (R6 logic), s_setprio(3).
//   - Blocks 256..511: heaters, s_setprio(0) — spin independent f32 FMAs to
//     raise utilization (and thus SCLK), poll 16 DONE tags, exit when all
//     batches finish. Priority 0 => they only use issue slots workers leave
//     idle. One worker + one heater per CU (99 KB LDS, 16 waves — resident).
//   - All argmax compares on u64 bit-patterns (exact for nonneg f64:
//     IEEE order == unsigned order; d >= 0 always, no NaN).
//
// Barrier protocol (unchanged from R6): 4 self-tagged 8-B relaxed atomic
// words per 128-B slot, per (parity, batch, rank):
//   A = value_lo32<<32 | m<<16 | idx        (idx<65536, m<2048: 16b each)
//   B = value_hi32<<32 | m<<16 | idx
//   C = x_bits<<32     | m<<16 | y_hi16
//   D = y_lo16<<48     | z_bits<<16 | m
// No fences anywhere. Reuse safety: slot rewritten at m+2 only after its
// writer saw all tags m+1, which post only after every block read m.
// 0xAA poison tag = 0xAAAA != any m in [1,2048) => no init kernel.
// DONE tag for heaters: word 12 of (parity0, batch, rank0) slot — never
// touched by the barrier protocol (words 0-3 only); poison != magic.

#define N_PTS   65536
#define M_SAMP  2048
#define NT      512
#define BPB     16                  // worker blocks per batch
#define PTS_BLK (N_PTS / BPB)       // 4096
#define PPT     (PTS_BLK / NT)      // 8 points per thread
#define NWAVES  (NT / 64)           // 8
#define NBATCH  16
#define SLOT_U64 16                 // 128 B per slot
#define NWORK   (BPB * NBATCH)      // 256 worker blocks
#define NHEAT   256                 // heater blocks
#define DONE_MAGIC 0x600D600D600D600Dull

typedef unsigned long long u64;

__device__ __forceinline__ u64 ld_agent(const u64* a) {
  return __hip_atomic_load(a, __ATOMIC_RELAXED, __HIP_MEMORY_SCOPE_AGENT);
}
__device__ __forceinline__ void st_agent(u64* a, u64 v) {
  __hip_atomic_store(a, v, __ATOMIC_RELAXED, __HIP_MEMORY_SCOPE_AGENT);
}
// DONE word for batch b: (parity0, batch b, rank0) slot, word 12.
__device__ __forceinline__ u64* done_word(u64* ws, int b) {
  return ws + (size_t)b * BPB * SLOT_U64 + 12;
}

__global__ __launch_bounds__(NT, 2)
void fps_multi(const float* __restrict__ pts, int* __restrict__ out,
               u64* __restrict__ ws) {
  const int t = threadIdx.x;

  // ---------------- heater blocks ----------------
  if (blockIdx.x >= NWORK) {
    __builtin_amdgcn_s_setprio(0);
    float a0 = 1.0f + t, a1 = 2.0f + t, a2 = 3.0f, a3 = 4.0f;
    float a4 = 5.0f, a5 = 6.0f, a6 = 7.0f, a7 = 8.0f;
    const float k0 = 1.0000001f, k1 = 0.9999991f;
    for (;;) {
      for (int it = 0; it < 128; ++it) {   // 1024 independent FMAs per poll
        a0 = __builtin_fmaf(a0, k0, k1); a1 = __builtin_fmaf(a1, k0, k1);
        a2 = __builtin_fmaf(a2, k0, k1); a3 = __builtin_fmaf(a3, k0, k1);
        a4 = __builtin_fmaf(a4, k0, k1); a5 = __builtin_fmaf(a5, k0, k1);
        a6 = __builtin_fmaf(a6, k0, k1); a7 = __builtin_fmaf(a7, k0, k1);
      }
      const u64 w = ld_agent(done_word(ws, t & 15));
      if (__all(w == DONE_MAGIC)) break;
    }
    // Sink so the FMAs aren't dead code; condition is never true at runtime.
    const float s = ((a0 + a1) + (a2 + a3)) + ((a4 + a5) + (a6 + a7));
    if (s == -1234.56789f) st_agent(done_word(ws, t & 15) + 1, (u64)t);
    return;
  }

  // ---------------- worker blocks ----------------
  __builtin_amdgcn_s_setprio(3);
  const int rank = blockIdx.x & (BPB - 1);     // same mapping as R6's dim3(16,16)
  const int b    = blockIdx.x >> 4;
  const float* __restrict__ p = pts + (size_t)b * (size_t)(N_PTS * 3);
  int* __restrict__ o = out + (size_t)b * M_SAMP;
  const int base = rank * PTS_BLK;

  __shared__ float s_pts[PTS_BLK * 3];         // 48 KB slice
  __shared__ u64   s_bv[NWAVES];               // per-wave max (u64 bits)
  __shared__ int   s_bi[NWAVES];
  __shared__ float s_c[3];                     // broadcast centroid coords

  for (int i = t; i < PTS_BLK * 3; i += NT)
    s_pts[i] = p[base * 3 + i];
  if (rank == 0 && t == 0) o[0] = 0;
  if (t == 0) { s_c[0] = p[0]; s_c[1] = p[1]; s_c[2] = p[2]; }  // seed pt 0
  __syncthreads();

  // Own points pre-converted to f64 in registers; (double)x is exact.
  double pd[PPT][3];
  double md[PPT];
#pragma unroll
  for (int j = 0; j < PPT; ++j) {
    const int l = t + j * NT;
    pd[j][0] = (double)s_pts[3 * l + 0];
    pd[j][1] = (double)s_pts[3 * l + 1];
    pd[j][2] = (double)s_pts[3 * l + 2];
    md[j] = 1e10;
  }

  for (int m = 1; m < M_SAMP; ++m) {
    const double cx = (double)s_c[0];
    const double cy = (double)s_c[1];
    const double cz = (double)s_c[2];

    // u64 bit-compare == f64 compare for nonneg values; bestb=0 loses to any
    // d>0; if everything ties at +0.0 the default (own lowest index) is safe.
    u64 bestb = 0;
    int besti = base + t;

    // Indices base + t + j*NT ascend with j => strict '>' keeps the first
    // (lowest-index) maximum within a thread.
#pragma unroll
    for (int j = 0; j < PPT; ++j) {
      const double dx = __dsub_rn(pd[j][0], cx);
      const double dy = __dsub_rn(pd[j][1], cy);
      const double dz = __dsub_rn(pd[j][2], cz);
      const double d  = __dadd_rn(__dadd_rn(__dmul_rn(dx, dx),
                                            __dmul_rn(dy, dy)),
                                  __dmul_rn(dz, dz));
      const double nmd = fmin(md[j], d);
      md[j] = nmd;
      const u64 nb = (u64)__double_as_longlong(nmd);
      if (nb > bestb) { bestb = nb; besti = base + t + j * NT; }
    }

    // 64-lane butterfly argmax (u64 compare), min-index tie-break.
#pragma unroll
    for (int off = 32; off >= 1; off >>= 1) {
      const u64 ov = __shfl_xor(bestb, off, 64);
      const int oi = __shfl_xor(besti, off, 64);
      if (ov > bestb || (ov == bestb && oi < besti)) { bestb = ov; besti = oi; }
    }
    if ((t & 63) == 0) { s_bv[t >> 6] = bestb; s_bi[t >> 6] = besti; }
    __syncthreads();

    // Wave 0: finish block reduction, publish, poll, cross-block reduce.
    if (t < 64) {
      if (t < NWAVES) {
        bestb = s_bv[t]; besti = s_bi[t];
#pragma unroll
        for (int off = NWAVES / 2; off >= 1; off >>= 1) {
          const u64 ov = __shfl_xor(bestb, off, 64);
          const int oi = __shfl_xor(besti, off, 64);
          if (ov > bestb || (ov == bestb && oi < besti)) { bestb = ov; besti = oi; }
        }
      }
      const u64 mm  = (u64)(unsigned)m;
      const u64 grp = (u64)(((m & 1) * NBATCH + b) * BPB);
      if (t == 0) {
        u64* slot = ws + (grp + rank) * SLOT_U64;
        const int l = besti - base;           // block winner is in our slice
        const unsigned xb = __float_as_uint(s_pts[3 * l + 0]);
        const unsigned yb = __float_as_uint(s_pts[3 * l + 1]);
        const unsigned zb = __float_as_uint(s_pts[3 * l + 2]);
        const u64 ti = (mm << 16) | (u64)(unsigned)besti;
        st_agent(&slot[0], (bestb << 32) | ti);                       // A
        st_agent(&slot[1], (bestb & 0xFFFFFFFF00000000ull) | ti);     // B
        st_agent(&slot[2], ((u64)xb << 32) | (mm << 16) | (u64)(yb >> 16));          // C
        st_agent(&slot[3], ((u64)(yb & 0xFFFFu) << 48) | ((u64)zb << 16) | mm);      // D
      }
      if (t < BPB) {
        const u64* rs = ws + (grp + t) * SLOT_U64;
        u64 A, B, C, D;
        for (;;) {
          A = ld_agent(rs + 0);
          B = ld_agent(rs + 1);
          C = ld_agent(rs + 2);
          D = ld_agent(rs + 3);
          const bool ok = (((A >> 16) & 0xFFFFull) == mm) &
                          (((B >> 16) & 0xFFFFull) == mm) &
                          (((C >> 16) & 0xFFFFull) == mm) &
                          ((D & 0xFFFFull) == mm);
          if (ok) break;
        }
        u64 v = (B & 0xFFFFFFFF00000000ull) | (A >> 32);   // f64 bits as u64
        int i = (int)(A & 0xFFFFull);
        float fx = __uint_as_float((unsigned)(C >> 32));
        float fy = __uint_as_float((unsigned)(((C & 0xFFFFull) << 16) | (D >> 48)));
        float fz = __uint_as_float((unsigned)((D >> 16) & 0xFFFFFFFFull));
        int r = t;                              // contributing rank
#pragma unroll
        for (int off = BPB / 2; off >= 1; off >>= 1) {
          const u64 ov = __shfl_xor(v, off, 64);
          const int oi = __shfl_xor(i, off, 64);
          const int orr = __shfl_xor(r, off, 64);
          if (ov > v || (ov == v && oi < i)) { v = ov; i = oi; r = orr; }
        }
        // Lanes 0..15 agree on winner rank r; pull its coords by shuffle.
        fx = __shfl(fx, r, 64);
        fy = __shfl(fy, r, 64);
        fz = __shfl(fz, r, 64);
        if (t == 0) {
          s_c[0] = fx; s_c[1] = fy; s_c[2] = fz;
          if (rank == 0) o[m] = i;
        }
      }
    }
    __syncthreads();
  }

  // Tell the heaters this batch is done (one writer per batch).
  if (rank == 0 && t == 0) st_agent(done_word(ws, b), DONE_MAGIC);
}

extern "C" void kernel_launch(void* const* d_in, const int* in_sizes, int n_in,
                              void* d_out, int out_size, void* d_ws, size_t ws_size,
                              hipStream_t stream) {
  const float* pts = (const float*)d_in[0];
  int* out = (int*)d_out;
  // ws usage: 2 * 16 * 16 slots * 128 B = 64 KB (DONE words live inside
  // unused slot padding — no extra space needed).
  hipLaunchKernelGGL(fps_multi, dim3(NWORK + NHEAT), dim3(NT), 0, stream,
                     pts, out, (u64*)d_ws);
}